// Round 7
// baseline (5468.850 us; speedup 1.0000x reference)
//
#include <hip/hip_runtime.h>
#include <hip/hip_bf16.h>
#include <math.h>

// ---------------------------------------------------------------------------
// Generalised gated MoE U-net, B=2048, E=4, W=10, fp32 throughout.
// Round 7: colsum reduced redundantly per conv block (gate_reduce kernels
//   deleted -> 5 fewer device-wide serialization points); mask regs 18->9 on
//   H%4==0 layers; __launch_bounds__(256,5) to push 4->5 blocks/CU.
//   Conv core otherwise = R6 (4-row strip, CG=2, ping-pong prefetch, fused
//   pool, fused final 1x1, XCD swizzle, inline gate finalize).
// ---------------------------------------------------------------------------

constexpr int BATCH = 2048;

// ---------------- workspace layout (in floats) ----------------
constexpr size_t PADF    = 1024;                       // 4KB guard pads
constexpr size_t F_CONV1 = (size_t)BATCH * 10 * 784;
constexpr size_t F_XPAD  = (size_t)BATCH * 784;
constexpr size_t F_P1    = (size_t)BATCH * 10 * 196;
constexpr size_t F_CONV2 = F_P1;
constexpr size_t F_P2    = (size_t)BATCH * 10 * 49;
constexpr size_t F_CONV3 = (size_t)BATCH * 20 * 49;
constexpr size_t F_UP3   = (size_t)BATCH * 20 * 196;
constexpr size_t F_M4    = F_P1;
constexpr size_t F_UP4   = F_CONV1;

constexpr size_t O_CONV1 = PADF;
constexpr size_t O_Z2    = O_CONV1 + F_CONV1 + PADF;
constexpr size_t O_XPAD  = O_Z2;
constexpr size_t O_P1    = O_XPAD + F_XPAD + PADF;
constexpr size_t O_CONV2 = O_P1 + F_P1 + PADF;
constexpr size_t O_P2    = O_CONV2 + F_CONV2 + PADF;
constexpr size_t O_CONV3 = O_P2 + F_P2 + PADF;
constexpr size_t O_UP3   = O_CONV3 + F_CONV3 + PADF;
constexpr size_t O_M4    = O_UP3 + F_UP3 + PADF;
constexpr size_t O_UP4   = O_Z2;                        // overlays dead xpad..up3
constexpr size_t O_GRAW  = O_M4 + F_M4 + PADF;          // after m4 zone
constexpr size_t WS_FLOATS = O_GRAW + 5 * (size_t)BATCH * 4 + PADF;

__device__ __forceinline__ float softplusf(float z) {
    return fmaxf(z, 0.0f) + log1pf(expf(-fabsf(z)));
}

__device__ __forceinline__ float4 ld4(const float* p) {
    return *(const float4*)p;
}

constexpr int cdivc(int a, int b) { return (a + b - 1) / b; }
constexpr int pb4(int H, int W) {          // 4-row strips; exact mult of 256
    return cdivc(BATCH * ((H + 3) / 4) * W, 256);
}

// ---------------- gate: block per sample, float4 path ----------------------
template <int C1HW, int C2HW>
__global__ __launch_bounds__(256) void gate_block_v4(
    const float* __restrict__ x1, const float* __restrict__ x2,
    const float* __restrict__ gw, const float* __restrict__ gb,
    const float* __restrict__ nw, const float* __restrict__ nb,
    const float* __restrict__ eps,
    float* __restrict__ graw)
{
    constexpr int DV = (C1HW + C2HW) / 4;
    const int b   = blockIdx.x;
    const int tid = threadIdx.x;

    float ga0 = 0.f, ga1 = 0.f, ga2 = 0.f, ga3 = 0.f;
    float na0 = 0.f, na1 = 0.f, na2 = 0.f, na3 = 0.f;

    for (int g = tid; g < DV; g += 256) {
        const int d = g * 4;
        float4 xv;
        if constexpr (C2HW > 0) {
            xv = (d < C1HW) ? ld4(x1 + (size_t)b * C1HW + d)
                            : ld4(x2 + (size_t)b * C2HW + (d - C1HW));
        } else {
            xv = ld4(x1 + (size_t)b * C1HW + d);
        }
        const float xs[4] = {xv.x, xv.y, xv.z, xv.w};
        #pragma unroll
        for (int j = 0; j < 4; ++j) {
            const float val = xs[j];
            const float4 gv = ((const float4*)gw)[d + j];
            const float4 nv = ((const float4*)nw)[d + j];
            ga0 = fmaf(val, gv.x, ga0); ga1 = fmaf(val, gv.y, ga1);
            ga2 = fmaf(val, gv.z, ga2); ga3 = fmaf(val, gv.w, ga3);
            na0 = fmaf(val, nv.x, na0); na1 = fmaf(val, nv.y, na1);
            na2 = fmaf(val, nv.z, na2); na3 = fmaf(val, nv.w, na3);
        }
    }
    #pragma unroll
    for (int m = 32; m >= 1; m >>= 1) {
        ga0 += __shfl_xor(ga0, m, 64); ga1 += __shfl_xor(ga1, m, 64);
        ga2 += __shfl_xor(ga2, m, 64); ga3 += __shfl_xor(ga3, m, 64);
        na0 += __shfl_xor(na0, m, 64); na1 += __shfl_xor(na1, m, 64);
        na2 += __shfl_xor(na2, m, 64); na3 += __shfl_xor(na3, m, 64);
    }
    __shared__ float red[4][8];
    const int wave = tid >> 6, lane = tid & 63;
    if (lane == 0) {
        red[wave][0] = ga0; red[wave][1] = ga1; red[wave][2] = ga2; red[wave][3] = ga3;
        red[wave][4] = na0; red[wave][5] = na1; red[wave][6] = na2; red[wave][7] = na3;
    }
    __syncthreads();
    if (tid == 0) {
        float G[8];
        #pragma unroll
        for (int i = 0; i < 8; ++i)
            G[i] = red[0][i] + red[1][i] + red[2][i] + red[3][i];
        #pragma unroll
        for (int e = 0; e < 4; ++e) {
            graw[b * 4 + e] = G[e] + gb[e] + eps[e] * softplusf(G[4 + e] + nb[e]);
        }
    }
}

// scalar variant (D=490)
template <int D>
__global__ __launch_bounds__(256) void gate_block_s(
    const float* __restrict__ x1,
    const float* __restrict__ gw, const float* __restrict__ gb,
    const float* __restrict__ nw, const float* __restrict__ nb,
    const float* __restrict__ eps,
    float* __restrict__ graw)
{
    const int b   = blockIdx.x;
    const int tid = threadIdx.x;

    float ga0 = 0.f, ga1 = 0.f, ga2 = 0.f, ga3 = 0.f;
    float na0 = 0.f, na1 = 0.f, na2 = 0.f, na3 = 0.f;

    for (int d = tid; d < D; d += 256) {
        const float val = x1[(size_t)b * D + d];
        const float4 gv = ((const float4*)gw)[d];
        const float4 nv = ((const float4*)nw)[d];
        ga0 = fmaf(val, gv.x, ga0); ga1 = fmaf(val, gv.y, ga1);
        ga2 = fmaf(val, gv.z, ga2); ga3 = fmaf(val, gv.w, ga3);
        na0 = fmaf(val, nv.x, na0); na1 = fmaf(val, nv.y, na1);
        na2 = fmaf(val, nv.z, na2); na3 = fmaf(val, nv.w, na3);
    }
    #pragma unroll
    for (int m = 32; m >= 1; m >>= 1) {
        ga0 += __shfl_xor(ga0, m, 64); ga1 += __shfl_xor(ga1, m, 64);
        ga2 += __shfl_xor(ga2, m, 64); ga3 += __shfl_xor(ga3, m, 64);
        na0 += __shfl_xor(na0, m, 64); na1 += __shfl_xor(na1, m, 64);
        na2 += __shfl_xor(na2, m, 64); na3 += __shfl_xor(na3, m, 64);
    }
    __shared__ float red[4][8];
    const int wave = tid >> 6, lane = tid & 63;
    if (lane == 0) {
        red[wave][0] = ga0; red[wave][1] = ga1; red[wave][2] = ga2; red[wave][3] = ga3;
        red[wave][4] = na0; red[wave][5] = na1; red[wave][6] = na2; red[wave][7] = na3;
    }
    __syncthreads();
    if (tid == 0) {
        float G[8];
        #pragma unroll
        for (int i = 0; i < 8; ++i)
            G[i] = red[0][i] + red[1][i] + red[2][i] + red[3][i];
        #pragma unroll
        for (int e = 0; e < 4; ++e) {
            graw[b * 4 + e] = G[e] + gb[e] + eps[e] * softplusf(G[4 + e] + nb[e]);
        }
    }
}

// ---------------- MoE conv 3x3 SAME + relu + gated sum ---------------------
// Thread = (b, w, 4-row strip) x CG=2 couts x 4 experts. Ping-pong tap
// prefetch over ci. Colsum over graw reduced per block (no extra kernel).
// Gate finalize (top-k + masked softmax) inlined. POOL: fused 2x2 maxpool.
// FINAL: fused 1x1 conv -> atomicAdd partials into out.
template <int CIN1, int CIN2, int COUT, int H, int W, int POOL, int FINAL>
__global__ __launch_bounds__(256, 5) void moe_conv4(
    const float* __restrict__ x1, const float* __restrict__ x2,
    const float* __restrict__ cw, const float* __restrict__ cb,
    const float* __restrict__ graw, const int* __restrict__ kp,
    float* __restrict__ out, float* __restrict__ pout,
    const float* __restrict__ wl, const float* __restrict__ bl)
{
    constexpr int CIN = CIN1 + CIN2;
    constexpr int CG  = 2;
    constexpr int NCG = COUT / CG;
    constexpr int HG  = (H + 3) / 4;
    constexpr int TOTAL = BATCH * HG * W;
    constexpr bool EXACT = (H % 4 == 0);   // all strip middle rows valid

    __shared__ __align__(16) float wlds[CIN * 72];   // [ci][k][j*4+e]
    __shared__ float red[4][4];

    const unsigned bid = blockIdx.x;
    const unsigned xcd = bid & 7u;
    const unsigned sub = bid >> 3;
    const unsigned cg  = sub % NCG;
    const unsigned tl  = sub / NCG;
    const unsigned tile = tl * 8u + xcd;
    const int c0 = (int)cg * CG;

    // stage weights into LDS
    for (int idx = threadIdx.x; idx < CIN * 72; idx += 256) {
        const int ci = idx / 72;
        const int r  = idx % 72;
        const int k  = r / 8;
        const int je = r % 8;
        wlds[idx] = cw[((size_t)((je & 3) * COUT + c0 + (je >> 2)) * CIN + ci) * 9 + k];
    }
    // per-block colsum reduce over graw (replaces gate_reduce kernel)
    {
        float a0 = 0.f, a1 = 0.f, a2 = 0.f, a3 = 0.f;
        for (int bb = threadIdx.x; bb < BATCH; bb += 256) {
            const float4 v = ld4(graw + bb * 4);
            a0 += v.x; a1 += v.y; a2 += v.z; a3 += v.w;
        }
        #pragma unroll
        for (int m = 32; m >= 1; m >>= 1) {
            a0 += __shfl_xor(a0, m, 64); a1 += __shfl_xor(a1, m, 64);
            a2 += __shfl_xor(a2, m, 64); a3 += __shfl_xor(a3, m, 64);
        }
        const int wave = threadIdx.x >> 6, lane = threadIdx.x & 63;
        if (lane == 0) {
            red[wave][0] = a0; red[wave][1] = a1;
            red[wave][2] = a2; red[wave][3] = a3;
        }
    }
    __syncthreads();

    const int t = (int)tile * 256 + (int)threadIdx.x;
    if (t >= TOTAL) return;                    // TOTAL % 256 == 0: never taken
    const int b  = t / (HG * W);
    const int r  = t - b * (HG * W);
    const int hg = r / W;
    const int w  = r - hg * W;
    const int h0 = hg * 4;

    // ---- inline gate finalize: top-k (by colsum) + masked softmax ----
    float gt[4];
    {
        float cs[4], gr[4];
        #pragma unroll
        for (int e = 0; e < 4; ++e) {
            cs[e] = red[0][e] + red[1][e] + red[2][e] + red[3][e];
            gr[e] = graw[b * 4 + e];
        }
        int k = kp[0];
        k = (k < 1) ? 1 : (k > 4 ? 4 : k);
        bool sel[4] = {false, false, false, false};
        for (int it = 0; it < k; ++it) {
            int bi = 0; float bv = -INFINITY;
            #pragma unroll
            for (int e = 0; e < 4; ++e)
                if (!sel[e] && cs[e] > bv) { bv = cs[e]; bi = e; }
            sel[bi] = true;
        }
        float g[4];
        #pragma unroll
        for (int e = 0; e < 4; ++e) g[e] = sel[e] ? gr[e] : 0.0f;
        const float mx = fmaxf(fmaxf(g[0], g[1]), fmaxf(g[2], g[3]));
        const float e0 = expf(g[0] - mx), e1 = expf(g[1] - mx);
        const float e2 = expf(g[2] - mx), e3 = expf(g[3] - mx);
        const float inv = 1.0f / (e0 + e1 + e2 + e3);
        gt[0] = e0 * inv; gt[1] = e1 * inv; gt[2] = e2 * inv; gt[3] = e3 * inv;
    }

    // ---- tap masks ----
    // EXACT: only rows 0 and 5 of the 6-row window can be invalid -> 9 regs.
    // general: mrow[6] + mcol[3] -> 9 regs, 2 muls per tap.
    float mcol[3], mtop[3], mbot[3];
    float mrow[6];
    if constexpr (EXACT) {
        const float ctop = (h0 > 0) ? 1.0f : 0.0f;
        const float cbot = (h0 + 4 < H) ? 1.0f : 0.0f;
        #pragma unroll
        for (int dc = 0; dc < 3; ++dc) {
            const int xx = w - 1 + dc;
            const float mc = (xx >= 0 && xx < W) ? 1.0f : 0.0f;
            mcol[dc] = mc; mtop[dc] = mc * ctop; mbot[dc] = mc * cbot;
        }
    } else {
        #pragma unroll
        for (int rr = 0; rr < 6; ++rr) {
            const int y = h0 - 1 + rr;
            mrow[rr] = (y >= 0 && y < H) ? 1.0f : 0.0f;
        }
        #pragma unroll
        for (int dc = 0; dc < 3; ++dc) {
            const int xx = w - 1 + dc;
            mcol[dc] = (xx >= 0 && xx < W) ? 1.0f : 0.0f;
        }
    }
    const int base = (h0 - 1) * W + (w - 1);   // may be negative; pads guard

    float acc[4][CG][4];
    #pragma unroll
    for (int j = 0; j < CG; ++j) {
        #pragma unroll
        for (int e = 0; e < 4; ++e) {
            const float bv = cb[e * COUT + c0 + j];
            #pragma unroll
            for (int rr = 0; rr < 4; ++rr) acc[rr][j][e] = bv;
        }
    }

    const float* xb1 = x1 + (size_t)b * CIN1 * (H * W);
    const float* xb2 = (CIN2 > 0) ? (x2 + (size_t)b * CIN2 * (H * W)) : nullptr;

    auto xplane = [&](int ci) -> const float* {
        if constexpr (CIN2 > 0)
            return (ci < CIN1) ? (xb1 + ci * (H * W)) : (xb2 + (ci - CIN1) * (H * W));
        else
            return xb1 + ci * (H * W);
    };
    auto load_taps = [&](int ci, float v[6][3]) {
        const float* xp = xplane(ci);
        #pragma unroll
        for (int rr = 0; rr < 6; ++rr)
            #pragma unroll
            for (int dc = 0; dc < 3; ++dc)
                v[rr][dc] = xp[base + rr * W + dc];
    };
    auto fma_taps = [&](int ci, const float v[6][3]) {
        float mv[6][3];
        if constexpr (EXACT) {
            #pragma unroll
            for (int dc = 0; dc < 3; ++dc) {
                mv[0][dc] = v[0][dc] * mtop[dc];
                mv[1][dc] = v[1][dc] * mcol[dc];
                mv[2][dc] = v[2][dc] * mcol[dc];
                mv[3][dc] = v[3][dc] * mcol[dc];
                mv[4][dc] = v[4][dc] * mcol[dc];
                mv[5][dc] = v[5][dc] * mbot[dc];
            }
        } else {
            #pragma unroll
            for (int rr = 0; rr < 6; ++rr)
                #pragma unroll
                for (int dc = 0; dc < 3; ++dc)
                    mv[rr][dc] = (v[rr][dc] * mcol[dc]) * mrow[rr];
        }
        const float4* wp = (const float4*)&wlds[ci * 72];
        #pragma unroll
        for (int k = 0; k < 9; ++k) {
            const float4 wA = wp[k * 2];
            const float4 wB = wp[k * 2 + 1];
            const int kh = k / 3, kw = k % 3;
            #pragma unroll
            for (int rr = 0; rr < 4; ++rr) {
                const float tap = mv[rr + kh][kw];
                acc[rr][0][0] = fmaf(tap, wA.x, acc[rr][0][0]);
                acc[rr][0][1] = fmaf(tap, wA.y, acc[rr][0][1]);
                acc[rr][0][2] = fmaf(tap, wA.z, acc[rr][0][2]);
                acc[rr][0][3] = fmaf(tap, wA.w, acc[rr][0][3]);
                acc[rr][1][0] = fmaf(tap, wB.x, acc[rr][1][0]);
                acc[rr][1][1] = fmaf(tap, wB.y, acc[rr][1][1]);
                acc[rr][1][2] = fmaf(tap, wB.z, acc[rr][1][2]);
                acc[rr][1][3] = fmaf(tap, wB.w, acc[rr][1][3]);
            }
        }
    };

    // software pipeline: ping-pong prefetch one ci ahead
    float vA[6][3], vB[6][3];
    load_taps(0, vA);
    #pragma unroll 1
    for (int ci = 0; ci + 2 <= CIN; ci += 2) {
        load_taps(ci + 1, vB);
        fma_taps(ci, vA);
        if (ci + 2 < CIN) load_taps(ci + 2, vA);
        fma_taps(ci + 1, vB);
    }
    if constexpr (CIN & 1) {
        fma_taps(CIN - 1, vA);
    }

    // ---- epilogue: relu + gated sum ----
    float s[4][CG];
    #pragma unroll
    for (int rr = 0; rr < 4; ++rr)
        #pragma unroll
        for (int j = 0; j < CG; ++j)
            s[rr][j] = gt[0] * fmaxf(acc[rr][j][0], 0.f)
                     + gt[1] * fmaxf(acc[rr][j][1], 0.f)
                     + gt[2] * fmaxf(acc[rr][j][2], 0.f)
                     + gt[3] * fmaxf(acc[rr][j][3], 0.f);

    if constexpr (FINAL) {
        // fused 1x1: atomic partial (+ bias/NCG) into out [B,1,H,W]
        const float w0 = wl[c0], w1 = wl[c0 + 1];
        const float bshare = bl[0] * (1.0f / (float)NCG);
        float* op = out + (size_t)b * (H * W) + h0 * W + w;
        #pragma unroll
        for (int rr = 0; rr < 4; ++rr) {
            if (EXACT || h0 + rr < H)
                atomicAdd(&op[rr * W], s[rr][0] * w0 + s[rr][1] * w1 + bshare);
        }
    } else {
        #pragma unroll
        for (int j = 0; j < CG; ++j) {
            float* op = out + ((size_t)b * COUT + c0 + j) * (H * W) + h0 * W + w;
            #pragma unroll
            for (int rr = 0; rr < 4; ++rr)
                if (EXACT || h0 + rr < H) op[rr * W] = s[rr][j];
        }
    }

    if constexpr (POOL) {
        constexpr int H2 = H / 2, W2 = W / 2;
        #pragma unroll
        for (int j = 0; j < CG; ++j) {
            float cm0 = fmaxf(s[0][j], s[1][j]);
            float cm1 = fmaxf(s[2][j], s[3][j]);
            const float o0 = fmaxf(cm0, __shfl_xor(cm0, 1, 64));
            const float o1 = fmaxf(cm1, __shfl_xor(cm1, 1, 64));
            if ((w & 1) == 0) {
                const int pr0 = h0 >> 1;
                float* pp = pout + ((size_t)b * COUT + c0 + j) * (H2 * W2) + (w >> 1);
                if (EXACT || pr0     < H2) pp[pr0 * W2]       = o0;
                if (EXACT || pr0 + 1 < H2) pp[(pr0 + 1) * W2] = o1;
            }
        }
    }
}

// ---------------- bilinear x2 upsample, align_corners=True ----------------
template <int N>
__global__ __launch_bounds__(256) void upsample2(
    const float* __restrict__ in, float* __restrict__ out, int BC)
{
    constexpr int M = 2 * N;
    const int idx = blockIdx.x * 256 + threadIdx.x;
    const int total = BC * M * M;
    if (idx >= total) return;
    const int x = idx % M;
    int tmp = idx / M;
    const int y = tmp % M;
    const int bc = tmp / M;
    const float scale = (float)((double)(N - 1) / (double)(M - 1));
    const float cy = (float)y * scale;
    const float cx = (float)x * scale;
    const int iy0 = (int)floorf(cy);
    const int ix0 = (int)floorf(cx);
    const int iy1 = min(iy0 + 1, N - 1);
    const int ix1 = min(ix0 + 1, N - 1);
    const float wy = cy - (float)iy0;
    const float wx = cx - (float)ix0;
    const float* p = in + (size_t)bc * N * N;
    const float v00 = p[iy0 * N + ix0], v01 = p[iy0 * N + ix1];
    const float v10 = p[iy1 * N + ix0], v11 = p[iy1 * N + ix1];
    const float a0 = v00 * (1.0f - wy) + v10 * wy;
    const float a1 = v01 * (1.0f - wy) + v11 * wy;
    out[idx] = a0 * (1.0f - wx) + a1 * wx;
}

// ---------------------------------------------------------------------------
extern "C" void kernel_launch(void* const* d_in, const int* in_sizes, int n_in,
                              void* d_out, int out_size, void* d_ws, size_t ws_size,
                              hipStream_t stream)
{
    const float* x = (const float*)d_in[0];
    const float* cw[5]; const float* cb[5]; const float* gw[5]; const float* gb[5];
    const float* nw[5]; const float* nb[5]; const float* epsv[5];
    for (int l = 0; l < 5; ++l) {
        cw[l]   = (const float*)d_in[1 + 7 * l + 0];
        cb[l]   = (const float*)d_in[1 + 7 * l + 1];
        gw[l]   = (const float*)d_in[1 + 7 * l + 2];
        gb[l]   = (const float*)d_in[1 + 7 * l + 3];
        nw[l]   = (const float*)d_in[1 + 7 * l + 4];
        nb[l]   = (const float*)d_in[1 + 7 * l + 5];
        epsv[l] = (const float*)d_in[1 + 7 * l + 6];
    }
    const float* wlast = (const float*)d_in[36];
    const float* blast = (const float*)d_in[37];
    const int*   kp    = (const int*)d_in[38];
    float* out = (float*)d_out;
    float* ws  = (float*)d_ws;

    float* conv1 = ws + O_CONV1;
    float* xpad  = ws + O_XPAD;
    float* p1    = ws + O_P1;
    float* conv2 = ws + O_CONV2;
    float* p2    = ws + O_P2;
    float* conv3 = ws + O_CONV3;
    float* up3   = ws + O_UP3;
    float* m4    = ws + O_M4;
    float* up4   = ws + O_UP4;
    float* graw[5];
    for (int l = 0; l < 5; ++l)
        graw[l] = ws + O_GRAW + (size_t)l * BATCH * 4;

    // out zero for the fused-final atomics; padded input copy for conv1 taps
    hipMemsetAsync(out, 0, (size_t)out_size * sizeof(float), stream);
    hipMemcpyAsync(xpad, x, (size_t)BATCH * 784 * sizeof(float),
                   hipMemcpyDeviceToDevice, stream);

    #define CDIV(a) (((a) + 255) / 256)
    const int g1 = pb4(28, 28) * 5;   // 1568 * 5
    const int g2 = pb4(14, 14) * 5;   //  448 * 5
    const int g3 = pb4(7, 7)   * 10;  //  112 * 10
    const int g4 = pb4(14, 14) * 5;
    const int g5 = pb4(28, 28) * 5;

    // ---- layer 1: x [B,1,28,28] -> conv1 + p1 (fused pool)
    gate_block_v4<784, 0><<<BATCH, 256, 0, stream>>>(
        x, nullptr, gw[0], gb[0], nw[0], nb[0], epsv[0], graw[0]);
    moe_conv4<1, 0, 10, 28, 28, 1, 0><<<g1, 256, 0, stream>>>(
        xpad, nullptr, cw[0], cb[0], graw[0], kp, conv1, p1, nullptr, nullptr);

    // ---- layer 2: p1 -> conv2 + p2 (fused pool)
    gate_block_v4<1960, 0><<<BATCH, 256, 0, stream>>>(
        p1, nullptr, gw[1], gb[1], nw[1], nb[1], epsv[1], graw[1]);
    moe_conv4<10, 0, 10, 14, 14, 1, 0><<<g2, 256, 0, stream>>>(
        p1, nullptr, cw[1], cb[1], graw[1], kp, conv2, p2, nullptr, nullptr);

    // ---- layer 3: p2 -> conv3 -> up3
    gate_block_s<490><<<BATCH, 256, 0, stream>>>(
        p2, gw[2], gb[2], nw[2], nb[2], epsv[2], graw[2]);
    moe_conv4<10, 0, 20, 7, 7, 0, 0><<<g3, 256, 0, stream>>>(
        p2, nullptr, cw[2], cb[2], graw[2], kp, conv3, nullptr, nullptr, nullptr);
    upsample2<7><<<CDIV(BATCH * 20 * 196), 256, 0, stream>>>(conv3, up3, BATCH * 20);

    // ---- layer 4: [up3 | conv2] -> m4 -> up4
    gate_block_v4<3920, 1960><<<BATCH, 256, 0, stream>>>(
        up3, conv2, gw[3], gb[3], nw[3], nb[3], epsv[3], graw[3]);
    moe_conv4<20, 10, 10, 14, 14, 0, 0><<<g4, 256, 0, stream>>>(
        up3, conv2, cw[3], cb[3], graw[3], kp, m4, nullptr, nullptr, nullptr);
    upsample2<14><<<CDIV(BATCH * 10 * 784), 256, 0, stream>>>(m4, up4, BATCH * 10);

    // ---- layer 5: [up4 | conv1] -> fused (conv + gate + final 1x1) -> out
    gate_block_v4<7840, 7840><<<BATCH, 256, 0, stream>>>(
        up4, conv1, gw[4], gb[4], nw[4], nb[4], epsv[4], graw[4]);
    moe_conv4<10, 10, 10, 28, 28, 0, 1><<<g5, 256, 0, stream>>>(
        up4, conv1, cw[4], cb[4], graw[4], kp, out, nullptr, wlast, blast);
    #undef CDIV
}

// Round 8
// 911.689 us; speedup vs baseline: 5.9986x; 5.9986x over previous
//
#include <hip/hip_runtime.h>
#include <hip/hip_bf16.h>
#include <math.h>

// ---------------------------------------------------------------------------
// Generalised gated MoE U-net, B=2048, E=4, W=10, fp32 throughout.
// Round 8: REVERT __launch_bounds__(256,5) -> (256). R7's waves/EU=5 request
//   capped VGPR at 48 and spilled acc/taps to scratch (14.5 GB HBM traffic,
//   VALUBusy 7%). Natural allocation is 112 VGPR / 4 waves/SIMD.
//   Keep R7's good parts: colsum fused into conv preamble (no gate_reduce
//   kernels), 9-reg EXACT masks, fused pool/final, XCD swizzle.
// ---------------------------------------------------------------------------

constexpr int BATCH = 2048;

// ---------------- workspace layout (in floats) ----------------
constexpr size_t PADF    = 1024;                       // 4KB guard pads
constexpr size_t F_CONV1 = (size_t)BATCH * 10 * 784;
constexpr size_t F_XPAD  = (size_t)BATCH * 784;
constexpr size_t F_P1    = (size_t)BATCH * 10 * 196;
constexpr size_t F_CONV2 = F_P1;
constexpr size_t F_P2    = (size_t)BATCH * 10 * 49;
constexpr size_t F_CONV3 = (size_t)BATCH * 20 * 49;
constexpr size_t F_UP3   = (size_t)BATCH * 20 * 196;
constexpr size_t F_M4    = F_P1;
constexpr size_t F_UP4   = F_CONV1;

constexpr size_t O_CONV1 = PADF;
constexpr size_t O_Z2    = O_CONV1 + F_CONV1 + PADF;
constexpr size_t O_XPAD  = O_Z2;
constexpr size_t O_P1    = O_XPAD + F_XPAD + PADF;
constexpr size_t O_CONV2 = O_P1 + F_P1 + PADF;
constexpr size_t O_P2    = O_CONV2 + F_CONV2 + PADF;
constexpr size_t O_CONV3 = O_P2 + F_P2 + PADF;
constexpr size_t O_UP3   = O_CONV3 + F_CONV3 + PADF;
constexpr size_t O_M4    = O_UP3 + F_UP3 + PADF;
constexpr size_t O_UP4   = O_Z2;                        // overlays dead xpad..up3
constexpr size_t O_GRAW  = O_M4 + F_M4 + PADF;          // after m4 zone
constexpr size_t WS_FLOATS = O_GRAW + 5 * (size_t)BATCH * 4 + PADF;

__device__ __forceinline__ float softplusf(float z) {
    return fmaxf(z, 0.0f) + log1pf(expf(-fabsf(z)));
}

__device__ __forceinline__ float4 ld4(const float* p) {
    return *(const float4*)p;
}

constexpr int cdivc(int a, int b) { return (a + b - 1) / b; }
constexpr int pb4(int H, int W) {          // 4-row strips; exact mult of 256
    return cdivc(BATCH * ((H + 3) / 4) * W, 256);
}

// ---------------- gate: block per sample, float4 path ----------------------
template <int C1HW, int C2HW>
__global__ __launch_bounds__(256) void gate_block_v4(
    const float* __restrict__ x1, const float* __restrict__ x2,
    const float* __restrict__ gw, const float* __restrict__ gb,
    const float* __restrict__ nw, const float* __restrict__ nb,
    const float* __restrict__ eps,
    float* __restrict__ graw)
{
    constexpr int DV = (C1HW + C2HW) / 4;
    const int b   = blockIdx.x;
    const int tid = threadIdx.x;

    float ga0 = 0.f, ga1 = 0.f, ga2 = 0.f, ga3 = 0.f;
    float na0 = 0.f, na1 = 0.f, na2 = 0.f, na3 = 0.f;

    for (int g = tid; g < DV; g += 256) {
        const int d = g * 4;
        float4 xv;
        if constexpr (C2HW > 0) {
            xv = (d < C1HW) ? ld4(x1 + (size_t)b * C1HW + d)
                            : ld4(x2 + (size_t)b * C2HW + (d - C1HW));
        } else {
            xv = ld4(x1 + (size_t)b * C1HW + d);
        }
        const float xs[4] = {xv.x, xv.y, xv.z, xv.w};
        #pragma unroll
        for (int j = 0; j < 4; ++j) {
            const float val = xs[j];
            const float4 gv = ((const float4*)gw)[d + j];
            const float4 nv = ((const float4*)nw)[d + j];
            ga0 = fmaf(val, gv.x, ga0); ga1 = fmaf(val, gv.y, ga1);
            ga2 = fmaf(val, gv.z, ga2); ga3 = fmaf(val, gv.w, ga3);
            na0 = fmaf(val, nv.x, na0); na1 = fmaf(val, nv.y, na1);
            na2 = fmaf(val, nv.z, na2); na3 = fmaf(val, nv.w, na3);
        }
    }
    #pragma unroll
    for (int m = 32; m >= 1; m >>= 1) {
        ga0 += __shfl_xor(ga0, m, 64); ga1 += __shfl_xor(ga1, m, 64);
        ga2 += __shfl_xor(ga2, m, 64); ga3 += __shfl_xor(ga3, m, 64);
        na0 += __shfl_xor(na0, m, 64); na1 += __shfl_xor(na1, m, 64);
        na2 += __shfl_xor(na2, m, 64); na3 += __shfl_xor(na3, m, 64);
    }
    __shared__ float red[4][8];
    const int wave = tid >> 6, lane = tid & 63;
    if (lane == 0) {
        red[wave][0] = ga0; red[wave][1] = ga1; red[wave][2] = ga2; red[wave][3] = ga3;
        red[wave][4] = na0; red[wave][5] = na1; red[wave][6] = na2; red[wave][7] = na3;
    }
    __syncthreads();
    if (tid == 0) {
        float G[8];
        #pragma unroll
        for (int i = 0; i < 8; ++i)
            G[i] = red[0][i] + red[1][i] + red[2][i] + red[3][i];
        #pragma unroll
        for (int e = 0; e < 4; ++e) {
            graw[b * 4 + e] = G[e] + gb[e] + eps[e] * softplusf(G[4 + e] + nb[e]);
        }
    }
}

// scalar variant (D=490)
template <int D>
__global__ __launch_bounds__(256) void gate_block_s(
    const float* __restrict__ x1,
    const float* __restrict__ gw, const float* __restrict__ gb,
    const float* __restrict__ nw, const float* __restrict__ nb,
    const float* __restrict__ eps,
    float* __restrict__ graw)
{
    const int b   = blockIdx.x;
    const int tid = threadIdx.x;

    float ga0 = 0.f, ga1 = 0.f, ga2 = 0.f, ga3 = 0.f;
    float na0 = 0.f, na1 = 0.f, na2 = 0.f, na3 = 0.f;

    for (int d = tid; d < D; d += 256) {
        const float val = x1[(size_t)b * D + d];
        const float4 gv = ((const float4*)gw)[d];
        const float4 nv = ((const float4*)nw)[d];
        ga0 = fmaf(val, gv.x, ga0); ga1 = fmaf(val, gv.y, ga1);
        ga2 = fmaf(val, gv.z, ga2); ga3 = fmaf(val, gv.w, ga3);
        na0 = fmaf(val, nv.x, na0); na1 = fmaf(val, nv.y, na1);
        na2 = fmaf(val, nv.z, na2); na3 = fmaf(val, nv.w, na3);
    }
    #pragma unroll
    for (int m = 32; m >= 1; m >>= 1) {
        ga0 += __shfl_xor(ga0, m, 64); ga1 += __shfl_xor(ga1, m, 64);
        ga2 += __shfl_xor(ga2, m, 64); ga3 += __shfl_xor(ga3, m, 64);
        na0 += __shfl_xor(na0, m, 64); na1 += __shfl_xor(na1, m, 64);
        na2 += __shfl_xor(na2, m, 64); na3 += __shfl_xor(na3, m, 64);
    }
    __shared__ float red[4][8];
    const int wave = tid >> 6, lane = tid & 63;
    if (lane == 0) {
        red[wave][0] = ga0; red[wave][1] = ga1; red[wave][2] = ga2; red[wave][3] = ga3;
        red[wave][4] = na0; red[wave][5] = na1; red[wave][6] = na2; red[wave][7] = na3;
    }
    __syncthreads();
    if (tid == 0) {
        float G[8];
        #pragma unroll
        for (int i = 0; i < 8; ++i)
            G[i] = red[0][i] + red[1][i] + red[2][i] + red[3][i];
        #pragma unroll
        for (int e = 0; e < 4; ++e) {
            graw[b * 4 + e] = G[e] + gb[e] + eps[e] * softplusf(G[4 + e] + nb[e]);
        }
    }
}

// ---------------- MoE conv 3x3 SAME + relu + gated sum ---------------------
// Thread = (b, w, 4-row strip) x CG=2 couts x 4 experts. Ping-pong tap
// prefetch over ci. Colsum over graw reduced per block (no extra kernel).
// Gate finalize (top-k + masked softmax) inlined. POOL: fused 2x2 maxpool.
// FINAL: fused 1x1 conv -> atomicAdd partials into out.
// NOTE: plain __launch_bounds__(256) — requesting 5 waves/EU caps VGPR at 48
// and spills (R7: 14.5 GB scratch traffic). Natural = 112 VGPR, 4 blocks/CU.
template <int CIN1, int CIN2, int COUT, int H, int W, int POOL, int FINAL>
__global__ __launch_bounds__(256) void moe_conv4(
    const float* __restrict__ x1, const float* __restrict__ x2,
    const float* __restrict__ cw, const float* __restrict__ cb,
    const float* __restrict__ graw, const int* __restrict__ kp,
    float* __restrict__ out, float* __restrict__ pout,
    const float* __restrict__ wl, const float* __restrict__ bl)
{
    constexpr int CIN = CIN1 + CIN2;
    constexpr int CG  = 2;
    constexpr int NCG = COUT / CG;
    constexpr int HG  = (H + 3) / 4;
    constexpr int TOTAL = BATCH * HG * W;
    constexpr bool EXACT = (H % 4 == 0);   // all strip middle rows valid

    __shared__ __align__(16) float wlds[CIN * 72];   // [ci][k][j*4+e]
    __shared__ float red[4][4];

    const unsigned bid = blockIdx.x;
    const unsigned xcd = bid & 7u;
    const unsigned sub = bid >> 3;
    const unsigned cg  = sub % NCG;
    const unsigned tl  = sub / NCG;
    const unsigned tile = tl * 8u + xcd;
    const int c0 = (int)cg * CG;

    // stage weights into LDS
    for (int idx = threadIdx.x; idx < CIN * 72; idx += 256) {
        const int ci = idx / 72;
        const int r  = idx % 72;
        const int k  = r / 8;
        const int je = r % 8;
        wlds[idx] = cw[((size_t)((je & 3) * COUT + c0 + (je >> 2)) * CIN + ci) * 9 + k];
    }
    // per-block colsum reduce over graw (replaces gate_reduce kernel)
    {
        float a0 = 0.f, a1 = 0.f, a2 = 0.f, a3 = 0.f;
        for (int bb = threadIdx.x; bb < BATCH; bb += 256) {
            const float4 v = ld4(graw + bb * 4);
            a0 += v.x; a1 += v.y; a2 += v.z; a3 += v.w;
        }
        #pragma unroll
        for (int m = 32; m >= 1; m >>= 1) {
            a0 += __shfl_xor(a0, m, 64); a1 += __shfl_xor(a1, m, 64);
            a2 += __shfl_xor(a2, m, 64); a3 += __shfl_xor(a3, m, 64);
        }
        const int wave = threadIdx.x >> 6, lane = threadIdx.x & 63;
        if (lane == 0) {
            red[wave][0] = a0; red[wave][1] = a1;
            red[wave][2] = a2; red[wave][3] = a3;
        }
    }
    __syncthreads();

    const int t = (int)tile * 256 + (int)threadIdx.x;
    if (t >= TOTAL) return;                    // TOTAL % 256 == 0: never taken
    const int b  = t / (HG * W);
    const int r  = t - b * (HG * W);
    const int hg = r / W;
    const int w  = r - hg * W;
    const int h0 = hg * 4;

    // ---- inline gate finalize: top-k (by colsum) + masked softmax ----
    float gt[4];
    {
        float cs[4], gr[4];
        #pragma unroll
        for (int e = 0; e < 4; ++e) {
            cs[e] = red[0][e] + red[1][e] + red[2][e] + red[3][e];
            gr[e] = graw[b * 4 + e];
        }
        int k = kp[0];
        k = (k < 1) ? 1 : (k > 4 ? 4 : k);
        bool sel[4] = {false, false, false, false};
        for (int it = 0; it < k; ++it) {
            int bi = 0; float bv = -INFINITY;
            #pragma unroll
            for (int e = 0; e < 4; ++e)
                if (!sel[e] && cs[e] > bv) { bv = cs[e]; bi = e; }
            sel[bi] = true;
        }
        float g[4];
        #pragma unroll
        for (int e = 0; e < 4; ++e) g[e] = sel[e] ? gr[e] : 0.0f;
        const float mx = fmaxf(fmaxf(g[0], g[1]), fmaxf(g[2], g[3]));
        const float e0 = expf(g[0] - mx), e1 = expf(g[1] - mx);
        const float e2 = expf(g[2] - mx), e3 = expf(g[3] - mx);
        const float inv = 1.0f / (e0 + e1 + e2 + e3);
        gt[0] = e0 * inv; gt[1] = e1 * inv; gt[2] = e2 * inv; gt[3] = e3 * inv;
    }

    // ---- tap masks ----
    float mcol[3], mtop[3], mbot[3];
    float mrow[6];
    if constexpr (EXACT) {
        const float ctop = (h0 > 0) ? 1.0f : 0.0f;
        const float cbot = (h0 + 4 < H) ? 1.0f : 0.0f;
        #pragma unroll
        for (int dc = 0; dc < 3; ++dc) {
            const int xx = w - 1 + dc;
            const float mc = (xx >= 0 && xx < W) ? 1.0f : 0.0f;
            mcol[dc] = mc; mtop[dc] = mc * ctop; mbot[dc] = mc * cbot;
        }
    } else {
        #pragma unroll
        for (int rr = 0; rr < 6; ++rr) {
            const int y = h0 - 1 + rr;
            mrow[rr] = (y >= 0 && y < H) ? 1.0f : 0.0f;
        }
        #pragma unroll
        for (int dc = 0; dc < 3; ++dc) {
            const int xx = w - 1 + dc;
            mcol[dc] = (xx >= 0 && xx < W) ? 1.0f : 0.0f;
        }
    }
    const int base = (h0 - 1) * W + (w - 1);   // may be negative; pads guard

    float acc[4][CG][4];
    #pragma unroll
    for (int j = 0; j < CG; ++j) {
        #pragma unroll
        for (int e = 0; e < 4; ++e) {
            const float bv = cb[e * COUT + c0 + j];
            #pragma unroll
            for (int rr = 0; rr < 4; ++rr) acc[rr][j][e] = bv;
        }
    }

    const float* xb1 = x1 + (size_t)b * CIN1 * (H * W);
    const float* xb2 = (CIN2 > 0) ? (x2 + (size_t)b * CIN2 * (H * W)) : nullptr;

    auto xplane = [&](int ci) -> const float* {
        if constexpr (CIN2 > 0)
            return (ci < CIN1) ? (xb1 + ci * (H * W)) : (xb2 + (ci - CIN1) * (H * W));
        else
            return xb1 + ci * (H * W);
    };
    auto load_taps = [&](int ci, float v[6][3]) {
        const float* xp = xplane(ci);
        #pragma unroll
        for (int rr = 0; rr < 6; ++rr)
            #pragma unroll
            for (int dc = 0; dc < 3; ++dc)
                v[rr][dc] = xp[base + rr * W + dc];
    };
    auto fma_taps = [&](int ci, const float v[6][3]) {
        float mv[6][3];
        if constexpr (EXACT) {
            #pragma unroll
            for (int dc = 0; dc < 3; ++dc) {
                mv[0][dc] = v[0][dc] * mtop[dc];
                mv[1][dc] = v[1][dc] * mcol[dc];
                mv[2][dc] = v[2][dc] * mcol[dc];
                mv[3][dc] = v[3][dc] * mcol[dc];
                mv[4][dc] = v[4][dc] * mcol[dc];
                mv[5][dc] = v[5][dc] * mbot[dc];
            }
        } else {
            #pragma unroll
            for (int rr = 0; rr < 6; ++rr)
                #pragma unroll
                for (int dc = 0; dc < 3; ++dc)
                    mv[rr][dc] = (v[rr][dc] * mcol[dc]) * mrow[rr];
        }
        const float4* wp = (const float4*)&wlds[ci * 72];
        #pragma unroll
        for (int k = 0; k < 9; ++k) {
            const float4 wA = wp[k * 2];
            const float4 wB = wp[k * 2 + 1];
            const int kh = k / 3, kw = k % 3;
            #pragma unroll
            for (int rr = 0; rr < 4; ++rr) {
                const float tap = mv[rr + kh][kw];
                acc[rr][0][0] = fmaf(tap, wA.x, acc[rr][0][0]);
                acc[rr][0][1] = fmaf(tap, wA.y, acc[rr][0][1]);
                acc[rr][0][2] = fmaf(tap, wA.z, acc[rr][0][2]);
                acc[rr][0][3] = fmaf(tap, wA.w, acc[rr][0][3]);
                acc[rr][1][0] = fmaf(tap, wB.x, acc[rr][1][0]);
                acc[rr][1][1] = fmaf(tap, wB.y, acc[rr][1][1]);
                acc[rr][1][2] = fmaf(tap, wB.z, acc[rr][1][2]);
                acc[rr][1][3] = fmaf(tap, wB.w, acc[rr][1][3]);
            }
        }
    };

    // software pipeline: ping-pong prefetch one ci ahead
    float vA[6][3], vB[6][3];
    load_taps(0, vA);
    #pragma unroll 1
    for (int ci = 0; ci + 2 <= CIN; ci += 2) {
        load_taps(ci + 1, vB);
        fma_taps(ci, vA);
        if (ci + 2 < CIN) load_taps(ci + 2, vA);
        fma_taps(ci + 1, vB);
    }
    if constexpr (CIN & 1) {
        fma_taps(CIN - 1, vA);
    }

    // ---- epilogue: relu + gated sum ----
    float s[4][CG];
    #pragma unroll
    for (int rr = 0; rr < 4; ++rr)
        #pragma unroll
        for (int j = 0; j < CG; ++j)
            s[rr][j] = gt[0] * fmaxf(acc[rr][j][0], 0.f)
                     + gt[1] * fmaxf(acc[rr][j][1], 0.f)
                     + gt[2] * fmaxf(acc[rr][j][2], 0.f)
                     + gt[3] * fmaxf(acc[rr][j][3], 0.f);

    if constexpr (FINAL) {
        // fused 1x1: atomic partial (+ bias/NCG) into out [B,1,H,W]
        const float w0 = wl[c0], w1 = wl[c0 + 1];
        const float bshare = bl[0] * (1.0f / (float)NCG);
        float* op = out + (size_t)b * (H * W) + h0 * W + w;
        #pragma unroll
        for (int rr = 0; rr < 4; ++rr) {
            if (EXACT || h0 + rr < H)
                atomicAdd(&op[rr * W], s[rr][0] * w0 + s[rr][1] * w1 + bshare);
        }
    } else {
        #pragma unroll
        for (int j = 0; j < CG; ++j) {
            float* op = out + ((size_t)b * COUT + c0 + j) * (H * W) + h0 * W + w;
            #pragma unroll
            for (int rr = 0; rr < 4; ++rr)
                if (EXACT || h0 + rr < H) op[rr * W] = s[rr][j];
        }
    }

    if constexpr (POOL) {
        constexpr int H2 = H / 2, W2 = W / 2;
        #pragma unroll
        for (int j = 0; j < CG; ++j) {
            float cm0 = fmaxf(s[0][j], s[1][j]);
            float cm1 = fmaxf(s[2][j], s[3][j]);
            const float o0 = fmaxf(cm0, __shfl_xor(cm0, 1, 64));
            const float o1 = fmaxf(cm1, __shfl_xor(cm1, 1, 64));
            if ((w & 1) == 0) {
                const int pr0 = h0 >> 1;
                float* pp = pout + ((size_t)b * COUT + c0 + j) * (H2 * W2) + (w >> 1);
                if (EXACT || pr0     < H2) pp[pr0 * W2]       = o0;
                if (EXACT || pr0 + 1 < H2) pp[(pr0 + 1) * W2] = o1;
            }
        }
    }
}

// ---------------- bilinear x2 upsample, align_corners=True ----------------
template <int N>
__global__ __launch_bounds__(256) void upsample2(
    const float* __restrict__ in, float* __restrict__ out, int BC)
{
    constexpr int M = 2 * N;
    const int idx = blockIdx.x * 256 + threadIdx.x;
    const int total = BC * M * M;
    if (idx >= total) return;
    const int x = idx % M;
    int tmp = idx / M;
    const int y = tmp % M;
    const int bc = tmp / M;
    const float scale = (float)((double)(N - 1) / (double)(M - 1));
    const float cy = (float)y * scale;
    const float cx = (float)x * scale;
    const int iy0 = (int)floorf(cy);
    const int ix0 = (int)floorf(cx);
    const int iy1 = min(iy0 + 1, N - 1);
    const int ix1 = min(ix0 + 1, N - 1);
    const float wy = cy - (float)iy0;
    const float wx = cx - (float)ix0;
    const float* p = in + (size_t)bc * N * N;
    const float v00 = p[iy0 * N + ix0], v01 = p[iy0 * N + ix1];
    const float v10 = p[iy1 * N + ix0], v11 = p[iy1 * N + ix1];
    const float a0 = v00 * (1.0f - wy) + v10 * wy;
    const float a1 = v01 * (1.0f - wy) + v11 * wy;
    out[idx] = a0 * (1.0f - wx) + a1 * wx;
}

// ---------------------------------------------------------------------------
extern "C" void kernel_launch(void* const* d_in, const int* in_sizes, int n_in,
                              void* d_out, int out_size, void* d_ws, size_t ws_size,
                              hipStream_t stream)
{
    const float* x = (const float*)d_in[0];
    const float* cw[5]; const float* cb[5]; const float* gw[5]; const float* gb[5];
    const float* nw[5]; const float* nb[5]; const float* epsv[5];
    for (int l = 0; l < 5; ++l) {
        cw[l]   = (const float*)d_in[1 + 7 * l + 0];
        cb[l]   = (const float*)d_in[1 + 7 * l + 1];
        gw[l]   = (const float*)d_in[1 + 7 * l + 2];
        gb[l]   = (const float*)d_in[1 + 7 * l + 3];
        nw[l]   = (const float*)d_in[1 + 7 * l + 4];
        nb[l]   = (const float*)d_in[1 + 7 * l + 5];
        epsv[l] = (const float*)d_in[1 + 7 * l + 6];
    }
    const float* wlast = (const float*)d_in[36];
    const float* blast = (const float*)d_in[37];
    const int*   kp    = (const int*)d_in[38];
    float* out = (float*)d_out;
    float* ws  = (float*)d_ws;

    float* conv1 = ws + O_CONV1;
    float* xpad  = ws + O_XPAD;
    float* p1    = ws + O_P1;
    float* conv2 = ws + O_CONV2;
    float* p2    = ws + O_P2;
    float* conv3 = ws + O_CONV3;
    float* up3   = ws + O_UP3;
    float* m4    = ws + O_M4;
    float* up4   = ws + O_UP4;
    float* graw[5];
    for (int l = 0; l < 5; ++l)
        graw[l] = ws + O_GRAW + (size_t)l * BATCH * 4;

    // out zero for the fused-final atomics; padded input copy for conv1 taps
    hipMemsetAsync(out, 0, (size_t)out_size * sizeof(float), stream);
    hipMemcpyAsync(xpad, x, (size_t)BATCH * 784 * sizeof(float),
                   hipMemcpyDeviceToDevice, stream);

    #define CDIV(a) (((a) + 255) / 256)
    const int g1 = pb4(28, 28) * 5;   // 1568 * 5
    const int g2 = pb4(14, 14) * 5;   //  448 * 5
    const int g3 = pb4(7, 7)   * 10;  //  112 * 10
    const int g4 = pb4(14, 14) * 5;
    const int g5 = pb4(28, 28) * 5;

    // ---- layer 1: x [B,1,28,28] -> conv1 + p1 (fused pool)
    gate_block_v4<784, 0><<<BATCH, 256, 0, stream>>>(
        x, nullptr, gw[0], gb[0], nw[0], nb[0], epsv[0], graw[0]);
    moe_conv4<1, 0, 10, 28, 28, 1, 0><<<g1, 256, 0, stream>>>(
        xpad, nullptr, cw[0], cb[0], graw[0], kp, conv1, p1, nullptr, nullptr);

    // ---- layer 2: p1 -> conv2 + p2 (fused pool)
    gate_block_v4<1960, 0><<<BATCH, 256, 0, stream>>>(
        p1, nullptr, gw[1], gb[1], nw[1], nb[1], epsv[1], graw[1]);
    moe_conv4<10, 0, 10, 14, 14, 1, 0><<<g2, 256, 0, stream>>>(
        p1, nullptr, cw[1], cb[1], graw[1], kp, conv2, p2, nullptr, nullptr);

    // ---- layer 3: p2 -> conv3 -> up3
    gate_block_s<490><<<BATCH, 256, 0, stream>>>(
        p2, gw[2], gb[2], nw[2], nb[2], epsv[2], graw[2]);
    moe_conv4<10, 0, 20, 7, 7, 0, 0><<<g3, 256, 0, stream>>>(
        p2, nullptr, cw[2], cb[2], graw[2], kp, conv3, nullptr, nullptr, nullptr);
    upsample2<7><<<CDIV(BATCH * 20 * 196), 256, 0, stream>>>(conv3, up3, BATCH * 20);

    // ---- layer 4: [up3 | conv2] -> m4 -> up4
    gate_block_v4<3920, 1960><<<BATCH, 256, 0, stream>>>(
        up3, conv2, gw[3], gb[3], nw[3], nb[3], epsv[3], graw[3]);
    moe_conv4<20, 10, 10, 14, 14, 0, 0><<<g4, 256, 0, stream>>>(
        up3, conv2, cw[3], cb[3], graw[3], kp, m4, nullptr, nullptr, nullptr);
    upsample2<14><<<CDIV(BATCH * 10 * 784), 256, 0, stream>>>(m4, up4, BATCH * 10);

    // ---- layer 5: [up4 | conv1] -> fused (conv + gate + final 1x1) -> out
    gate_block_v4<7840, 7840><<<BATCH, 256, 0, stream>>>(
        up4, conv1, gw[4], gb[4], nw[4], nb[4], epsv[4], graw[4]);
    moe_conv4<10, 10, 10, 28, 28, 0, 1><<<g5, 256, 0, stream>>>(
        up4, conv1, cw[4], cb[4], graw[4], kp, out, nullptr, wlast, blast);
    #undef CDIV
}

// Round 9
// 829.176 us; speedup vs baseline: 6.5955x; 1.0995x over previous
//
#include <hip/hip_runtime.h>
#include <hip/hip_bf16.h>
#include <math.h>

// ---------------------------------------------------------------------------
// Generalised gated MoE U-net, B=2048, E=4, W=10, fp32 throughout.
// Round 9: (a) restore R6's separate gate_reduce (R8's per-block colsum
//   preamble cost +40 us); (b) NEW quad-pixel conv (2 rows x 4 cols) for the
//   W=28 layers: aligned float4 tap loads (12 VMEM + 18 LDS per ci for 8
//   pixels vs 18+18 for 4), float4 conv writes, in-thread 2x2 pool;
//   (c) gates process 2 samples/block (halves gw/nw L2 re-reads).
// ---------------------------------------------------------------------------

constexpr int BATCH = 2048;

// ---------------- workspace layout (in floats) ----------------
constexpr size_t PADF    = 1024;                       // 4KB guard pads
constexpr size_t F_CONV1 = (size_t)BATCH * 10 * 784;
constexpr size_t F_XPAD  = (size_t)BATCH * 784;
constexpr size_t F_P1    = (size_t)BATCH * 10 * 196;
constexpr size_t F_CONV2 = F_P1;
constexpr size_t F_P2    = (size_t)BATCH * 10 * 49;
constexpr size_t F_CONV3 = (size_t)BATCH * 20 * 49;
constexpr size_t F_UP3   = (size_t)BATCH * 20 * 196;
constexpr size_t F_M4    = F_P1;
constexpr size_t F_UP4   = F_CONV1;

constexpr size_t O_CONV1 = PADF;
constexpr size_t O_Z2    = O_CONV1 + F_CONV1 + PADF;
constexpr size_t O_XPAD  = O_Z2;
constexpr size_t O_P1    = O_XPAD + F_XPAD + PADF;
constexpr size_t O_CONV2 = O_P1 + F_P1 + PADF;
constexpr size_t O_P2    = O_CONV2 + F_CONV2 + PADF;
constexpr size_t O_CONV3 = O_P2 + F_P2 + PADF;
constexpr size_t O_UP3   = O_CONV3 + F_CONV3 + PADF;
constexpr size_t O_M4    = O_UP3 + F_UP3 + PADF;
constexpr size_t O_UP4   = O_Z2;                        // overlays dead xpad..up3
constexpr size_t O_GRAW  = O_M4 + F_M4 + PADF;
constexpr size_t O_CS    = O_GRAW + 5 * (size_t)BATCH * 4;
constexpr size_t WS_FLOATS = O_CS + 5 * 64 + PADF;

__device__ __forceinline__ float softplusf(float z) {
    return fmaxf(z, 0.0f) + log1pf(expf(-fabsf(z)));
}

__device__ __forceinline__ float4 ld4(const float* p) {
    return *(const float4*)p;
}

constexpr int cdivc(int a, int b) { return (a + b - 1) / b; }
constexpr int pb4(int H, int W) {
    return cdivc(BATCH * ((H + 3) / 4) * W, 256);
}

// ---------------- gate: block per 2 samples, float4 path -------------------
template <int C1HW, int C2HW>
__global__ __launch_bounds__(256) void gate_block_v4(
    const float* __restrict__ x1, const float* __restrict__ x2,
    const float* __restrict__ gw, const float* __restrict__ gb,
    const float* __restrict__ nw, const float* __restrict__ nb,
    const float* __restrict__ eps,
    float* __restrict__ graw)
{
    constexpr int DV = (C1HW + C2HW) / 4;
    const int b0  = blockIdx.x * 2;
    const int tid = threadIdx.x;

    float ga[2][4] = {}, na[2][4] = {};

    for (int g = tid; g < DV; g += 256) {
        const int d = g * 4;
        float4 xv[2];
        #pragma unroll
        for (int ss = 0; ss < 2; ++ss) {
            const int b = b0 + ss;
            if constexpr (C2HW > 0) {
                xv[ss] = (d < C1HW) ? ld4(x1 + (size_t)b * C1HW + d)
                                    : ld4(x2 + (size_t)b * C2HW + (d - C1HW));
            } else {
                xv[ss] = ld4(x1 + (size_t)b * C1HW + d);
            }
        }
        #pragma unroll
        for (int j = 0; j < 4; ++j) {
            const float4 gv = ((const float4*)gw)[d + j];
            const float4 nv = ((const float4*)nw)[d + j];
            #pragma unroll
            for (int ss = 0; ss < 2; ++ss) {
                const float val = (&xv[ss].x)[j];
                ga[ss][0] = fmaf(val, gv.x, ga[ss][0]);
                ga[ss][1] = fmaf(val, gv.y, ga[ss][1]);
                ga[ss][2] = fmaf(val, gv.z, ga[ss][2]);
                ga[ss][3] = fmaf(val, gv.w, ga[ss][3]);
                na[ss][0] = fmaf(val, nv.x, na[ss][0]);
                na[ss][1] = fmaf(val, nv.y, na[ss][1]);
                na[ss][2] = fmaf(val, nv.z, na[ss][2]);
                na[ss][3] = fmaf(val, nv.w, na[ss][3]);
            }
        }
    }
    #pragma unroll
    for (int m = 32; m >= 1; m >>= 1) {
        #pragma unroll
        for (int ss = 0; ss < 2; ++ss)
            #pragma unroll
            for (int e = 0; e < 4; ++e) {
                ga[ss][e] += __shfl_xor(ga[ss][e], m, 64);
                na[ss][e] += __shfl_xor(na[ss][e], m, 64);
            }
    }
    __shared__ float red[4][16];
    const int wave = tid >> 6, lane = tid & 63;
    if (lane == 0) {
        #pragma unroll
        for (int ss = 0; ss < 2; ++ss)
            #pragma unroll
            for (int e = 0; e < 4; ++e) {
                red[wave][ss * 8 + e]     = ga[ss][e];
                red[wave][ss * 8 + 4 + e] = na[ss][e];
            }
    }
    __syncthreads();
    if (tid < 2) {
        const int ss = tid;
        #pragma unroll
        for (int e = 0; e < 4; ++e) {
            const float G = red[0][ss*8+e] + red[1][ss*8+e]
                          + red[2][ss*8+e] + red[3][ss*8+e];
            const float N = red[0][ss*8+4+e] + red[1][ss*8+4+e]
                          + red[2][ss*8+4+e] + red[3][ss*8+4+e];
            graw[(b0 + ss) * 4 + e] = G + gb[e] + eps[e] * softplusf(N + nb[e]);
        }
    }
}

// scalar variant (D=490)
template <int D>
__global__ __launch_bounds__(256) void gate_block_s(
    const float* __restrict__ x1,
    const float* __restrict__ gw, const float* __restrict__ gb,
    const float* __restrict__ nw, const float* __restrict__ nb,
    const float* __restrict__ eps,
    float* __restrict__ graw)
{
    const int b   = blockIdx.x;
    const int tid = threadIdx.x;

    float ga0 = 0.f, ga1 = 0.f, ga2 = 0.f, ga3 = 0.f;
    float na0 = 0.f, na1 = 0.f, na2 = 0.f, na3 = 0.f;

    for (int d = tid; d < D; d += 256) {
        const float val = x1[(size_t)b * D + d];
        const float4 gv = ((const float4*)gw)[d];
        const float4 nv = ((const float4*)nw)[d];
        ga0 = fmaf(val, gv.x, ga0); ga1 = fmaf(val, gv.y, ga1);
        ga2 = fmaf(val, gv.z, ga2); ga3 = fmaf(val, gv.w, ga3);
        na0 = fmaf(val, nv.x, na0); na1 = fmaf(val, nv.y, na1);
        na2 = fmaf(val, nv.z, na2); na3 = fmaf(val, nv.w, na3);
    }
    #pragma unroll
    for (int m = 32; m >= 1; m >>= 1) {
        ga0 += __shfl_xor(ga0, m, 64); ga1 += __shfl_xor(ga1, m, 64);
        ga2 += __shfl_xor(ga2, m, 64); ga3 += __shfl_xor(ga3, m, 64);
        na0 += __shfl_xor(na0, m, 64); na1 += __shfl_xor(na1, m, 64);
        na2 += __shfl_xor(na2, m, 64); na3 += __shfl_xor(na3, m, 64);
    }
    __shared__ float red[4][8];
    const int wave = tid >> 6, lane = tid & 63;
    if (lane == 0) {
        red[wave][0] = ga0; red[wave][1] = ga1; red[wave][2] = ga2; red[wave][3] = ga3;
        red[wave][4] = na0; red[wave][5] = na1; red[wave][6] = na2; red[wave][7] = na3;
    }
    __syncthreads();
    if (tid == 0) {
        float G[8];
        #pragma unroll
        for (int i = 0; i < 8; ++i)
            G[i] = red[0][i] + red[1][i] + red[2][i] + red[3][i];
        #pragma unroll
        for (int e = 0; e < 4; ++e) {
            graw[b * 4 + e] = G[e] + gb[e] + eps[e] * softplusf(G[4 + e] + nb[e]);
        }
    }
}

// ---------------- gate reduce: colsum over batch (1 block) -----------------
__global__ __launch_bounds__(256) void gate_reduce(
    const float* __restrict__ graw, float* __restrict__ cs)
{
    const int tid = threadIdx.x;
    float a0 = 0.f, a1 = 0.f, a2 = 0.f, a3 = 0.f;
    for (int b = tid; b < BATCH; b += 256) {
        const float4 v = ld4(graw + b * 4);
        a0 += v.x; a1 += v.y; a2 += v.z; a3 += v.w;
    }
    #pragma unroll
    for (int m = 32; m >= 1; m >>= 1) {
        a0 += __shfl_xor(a0, m, 64); a1 += __shfl_xor(a1, m, 64);
        a2 += __shfl_xor(a2, m, 64); a3 += __shfl_xor(a3, m, 64);
    }
    __shared__ float red[4][4];
    const int wave = tid >> 6, lane = tid & 63;
    if (lane == 0) {
        red[wave][0] = a0; red[wave][1] = a1; red[wave][2] = a2; red[wave][3] = a3;
    }
    __syncthreads();
    if (tid < 4) {
        cs[tid] = red[0][tid] + red[1][tid] + red[2][tid] + red[3][tid];
    }
}

// ---------------- inline gate finalize helper ------------------------------
__device__ __forceinline__ void gate_final(
    const float* __restrict__ graw, const float* __restrict__ colsum,
    const int* __restrict__ kp, int b, float gt[4])
{
    float cs[4], gr[4];
    #pragma unroll
    for (int e = 0; e < 4; ++e) { cs[e] = colsum[e]; gr[e] = graw[b * 4 + e]; }
    int k = kp[0];
    k = (k < 1) ? 1 : (k > 4 ? 4 : k);
    bool sel[4] = {false, false, false, false};
    for (int it = 0; it < k; ++it) {
        int bi = 0; float bv = -INFINITY;
        #pragma unroll
        for (int e = 0; e < 4; ++e)
            if (!sel[e] && cs[e] > bv) { bv = cs[e]; bi = e; }
        sel[bi] = true;
    }
    float g[4];
    #pragma unroll
    for (int e = 0; e < 4; ++e) g[e] = sel[e] ? gr[e] : 0.0f;
    const float mx = fmaxf(fmaxf(g[0], g[1]), fmaxf(g[2], g[3]));
    const float e0 = expf(g[0] - mx), e1 = expf(g[1] - mx);
    const float e2 = expf(g[2] - mx), e3 = expf(g[3] - mx);
    const float inv = 1.0f / (e0 + e1 + e2 + e3);
    gt[0] = e0 * inv; gt[1] = e1 * inv; gt[2] = e2 * inv; gt[3] = e3 * inv;
}

// ---------------- quad-pixel conv (H=W=28 only) ----------------------------
// Thread = (b, 2-row, 4-col quad) x CG=2 couts x 4 experts.
// Aligned float4 + 2 scalar tap loads per row (12 VMEM / ci for 8 pixels).
// POOL: in-thread 2x2 maxpool (no shuffles). FINAL: fused 1x1 via atomics.
template <int CIN1, int CIN2, int COUT, int POOL, int FINAL>
__global__ __launch_bounds__(256) void moe_conv_q4(
    const float* __restrict__ x1, const float* __restrict__ x2,
    const float* __restrict__ cw, const float* __restrict__ cb,
    const float* __restrict__ graw, const float* __restrict__ colsum,
    const int* __restrict__ kp,
    float* __restrict__ out, float* __restrict__ pout,
    const float* __restrict__ wl, const float* __restrict__ bl)
{
    constexpr int H = 28, W = 28;
    constexpr int CIN = CIN1 + CIN2;
    constexpr int CG  = 2;
    constexpr int NCG = COUT / CG;
    constexpr int TOTAL = BATCH * 14 * 7;     // 200704 = 784 * 256

    __shared__ __align__(16) float wlds[CIN * 72];   // [ci][k][j*4+e]

    const unsigned bid = blockIdx.x;
    const unsigned xcd = bid & 7u;
    const unsigned sub = bid >> 3;
    const unsigned cg  = sub % NCG;
    const unsigned tl  = sub / NCG;
    const unsigned tile = tl * 8u + xcd;
    const int c0 = (int)cg * CG;

    for (int idx = threadIdx.x; idx < CIN * 72; idx += 256) {
        const int ci = idx / 72;
        const int r  = idx % 72;
        const int k  = r / 8;
        const int je = r % 8;
        wlds[idx] = cw[((size_t)((je & 3) * COUT + c0 + (je >> 2)) * CIN + ci) * 9 + k];
    }
    __syncthreads();

    const int t = (int)tile * 256 + (int)threadIdx.x;
    if (t >= TOTAL) return;                    // exact multiple: never taken
    const int b  = t / 98;
    const int r  = t - b * 98;
    const int hh = r / 7;
    const int q  = r - hh * 7;
    const int h0 = 2 * hh;
    const int w0 = 4 * q;

    float gt[4];
    gate_final(graw, colsum, kp, b, gt);

    const float rt = (h0 > 0)      ? 1.0f : 0.0f;   // tap row h0-1
    const float rb = (h0 + 2 < H)  ? 1.0f : 0.0f;   // tap row h0+2
    const float cl = (w0 > 0)      ? 1.0f : 0.0f;   // tap col w0-1
    const float cr = (w0 + 4 < W)  ? 1.0f : 0.0f;   // tap col w0+4

    float acc[2][4][CG][4];                    // [row][pix][cout][expert]
    #pragma unroll
    for (int j = 0; j < CG; ++j) {
        #pragma unroll
        for (int e = 0; e < 4; ++e) {
            const float bv = cb[e * COUT + c0 + j];
            #pragma unroll
            for (int rr = 0; rr < 2; ++rr)
                #pragma unroll
                for (int p = 0; p < 4; ++p) acc[rr][p][j][e] = bv;
        }
    }

    const int rbase = (h0 - 1) * W + w0;       // may be negative; pads guard
    const float* xb1 = x1 + (size_t)b * CIN1 * (H * W);
    const float* xb2 = (CIN2 > 0) ? (x2 + (size_t)b * CIN2 * (H * W)) : nullptr;

    auto xplane = [&](int ci) -> const float* {
        if constexpr (CIN2 > 0)
            return (ci < CIN1) ? (xb1 + ci * (H * W)) : (xb2 + (ci - CIN1) * (H * W));
        else
            return xb1 + ci * (H * W);
    };
    // taps: v[4 rows][6 cols]; cols = w0-1 .. w0+4
    auto load_taps = [&](int ci, float v[4][6]) {
        const float* rp = xplane(ci) + rbase;
        #pragma unroll
        for (int rr = 0; rr < 4; ++rr) {
            const float4 c = ld4(rp + rr * W);         // aligned: 28%4==0, w0%4==0
            v[rr][0] = rp[rr * W - 1];
            v[rr][1] = c.x; v[rr][2] = c.y; v[rr][3] = c.z; v[rr][4] = c.w;
            v[rr][5] = rp[rr * W + 4];
        }
    };
    auto fma_taps = [&](int ci, const float v[4][6]) {
        float mv[4][6];
        #pragma unroll
        for (int rr = 0; rr < 4; ++rr) {
            #pragma unroll
            for (int c = 0; c < 6; ++c) mv[rr][c] = v[rr][c];
            mv[rr][0] *= cl;
            mv[rr][5] *= cr;
        }
        #pragma unroll
        for (int c = 0; c < 6; ++c) { mv[0][c] *= rt; mv[3][c] *= rb; }

        const float4* wp = (const float4*)&wlds[ci * 72];
        #pragma unroll
        for (int k = 0; k < 9; ++k) {
            const float4 wA = wp[k * 2];
            const float4 wB = wp[k * 2 + 1];
            const int kh = k / 3, kw = k % 3;
            #pragma unroll
            for (int rr = 0; rr < 2; ++rr) {
                #pragma unroll
                for (int p = 0; p < 4; ++p) {
                    const float tap = mv[rr + kh][p + kw];
                    acc[rr][p][0][0] = fmaf(tap, wA.x, acc[rr][p][0][0]);
                    acc[rr][p][0][1] = fmaf(tap, wA.y, acc[rr][p][0][1]);
                    acc[rr][p][0][2] = fmaf(tap, wA.z, acc[rr][p][0][2]);
                    acc[rr][p][0][3] = fmaf(tap, wA.w, acc[rr][p][0][3]);
                    acc[rr][p][1][0] = fmaf(tap, wB.x, acc[rr][p][1][0]);
                    acc[rr][p][1][1] = fmaf(tap, wB.y, acc[rr][p][1][1]);
                    acc[rr][p][1][2] = fmaf(tap, wB.z, acc[rr][p][1][2]);
                    acc[rr][p][1][3] = fmaf(tap, wB.w, acc[rr][p][1][3]);
                }
            }
        }
    };

    float vA[4][6], vB[4][6];
    load_taps(0, vA);
    #pragma unroll 1
    for (int ci = 0; ci + 2 <= CIN; ci += 2) {
        load_taps(ci + 1, vB);
        fma_taps(ci, vA);
        if (ci + 2 < CIN) load_taps(ci + 2, vA);
        fma_taps(ci + 1, vB);
    }
    if constexpr (CIN & 1) {
        fma_taps(CIN - 1, vA);
    }

    // ---- epilogue: relu + gated sum ----
    float s[2][4][CG];
    #pragma unroll
    for (int rr = 0; rr < 2; ++rr)
        #pragma unroll
        for (int p = 0; p < 4; ++p)
            #pragma unroll
            for (int j = 0; j < CG; ++j)
                s[rr][p][j] = gt[0] * fmaxf(acc[rr][p][j][0], 0.f)
                            + gt[1] * fmaxf(acc[rr][p][j][1], 0.f)
                            + gt[2] * fmaxf(acc[rr][p][j][2], 0.f)
                            + gt[3] * fmaxf(acc[rr][p][j][3], 0.f);

    if constexpr (FINAL) {
        const float w0f = wl[c0], w1f = wl[c0 + 1];
        const float bshare = bl[0] * (1.0f / (float)NCG);
        float* op = out + (size_t)b * (H * W) + h0 * W + w0;
        #pragma unroll
        for (int rr = 0; rr < 2; ++rr)
            #pragma unroll
            for (int p = 0; p < 4; ++p)
                atomicAdd(&op[rr * W + p],
                          s[rr][p][0] * w0f + s[rr][p][1] * w1f + bshare);
    } else {
        #pragma unroll
        for (int j = 0; j < CG; ++j) {
            float* op = out + ((size_t)b * COUT + c0 + j) * (H * W) + h0 * W + w0;
            #pragma unroll
            for (int rr = 0; rr < 2; ++rr) {
                float4 o = {s[rr][0][j], s[rr][1][j], s[rr][2][j], s[rr][3][j]};
                *(float4*)(op + rr * W) = o;
            }
        }
    }

    if constexpr (POOL) {
        constexpr int H2 = 14, W2 = 14;
        #pragma unroll
        for (int j = 0; j < CG; ++j) {
            float2 o;
            o.x = fmaxf(fmaxf(s[0][0][j], s[0][1][j]), fmaxf(s[1][0][j], s[1][1][j]));
            o.y = fmaxf(fmaxf(s[0][2][j], s[0][3][j]), fmaxf(s[1][2][j], s[1][3][j]));
            float* pp = pout + ((size_t)b * COUT + c0 + j) * (H2 * W2)
                        + hh * W2 + (w0 >> 1);
            *(float2*)pp = o;
        }
    }
}

// ---------------- generic 4-row strip conv (H=14 / H=7 layers) -------------
template <int CIN1, int CIN2, int COUT, int H, int W, int POOL>
__global__ __launch_bounds__(256) void moe_conv4(
    const float* __restrict__ x1, const float* __restrict__ x2,
    const float* __restrict__ cw, const float* __restrict__ cb,
    const float* __restrict__ graw, const float* __restrict__ colsum,
    const int* __restrict__ kp,
    float* __restrict__ out, float* __restrict__ pout)
{
    constexpr int CIN = CIN1 + CIN2;
    constexpr int CG  = 2;
    constexpr int NCG = COUT / CG;
    constexpr int HG  = (H + 3) / 4;
    constexpr int TOTAL = BATCH * HG * W;

    __shared__ __align__(16) float wlds[CIN * 72];

    const unsigned bid = blockIdx.x;
    const unsigned xcd = bid & 7u;
    const unsigned sub = bid >> 3;
    const unsigned cg  = sub % NCG;
    const unsigned tl  = sub / NCG;
    const unsigned tile = tl * 8u + xcd;
    const int c0 = (int)cg * CG;

    for (int idx = threadIdx.x; idx < CIN * 72; idx += 256) {
        const int ci = idx / 72;
        const int r  = idx % 72;
        const int k  = r / 8;
        const int je = r % 8;
        wlds[idx] = cw[((size_t)((je & 3) * COUT + c0 + (je >> 2)) * CIN + ci) * 9 + k];
    }
    __syncthreads();

    const int t = (int)tile * 256 + (int)threadIdx.x;
    if (t >= TOTAL) return;
    const int b  = t / (HG * W);
    const int r  = t - b * (HG * W);
    const int hg = r / W;
    const int w  = r - hg * W;
    const int h0 = hg * 4;

    float gt[4];
    gate_final(graw, colsum, kp, b, gt);

    float m[6][3];
    #pragma unroll
    for (int rr = 0; rr < 6; ++rr) {
        const int y = h0 - 1 + rr;
        const float my = (y >= 0 && y < H) ? 1.0f : 0.0f;
        #pragma unroll
        for (int dc = 0; dc < 3; ++dc) {
            const int xx = w - 1 + dc;
            m[rr][dc] = ((xx >= 0 && xx < W) ? 1.0f : 0.0f) * my;
        }
    }
    const int base = (h0 - 1) * W + (w - 1);

    float acc[4][CG][4];
    #pragma unroll
    for (int j = 0; j < CG; ++j) {
        #pragma unroll
        for (int e = 0; e < 4; ++e) {
            const float bv = cb[e * COUT + c0 + j];
            #pragma unroll
            for (int rr = 0; rr < 4; ++rr) acc[rr][j][e] = bv;
        }
    }

    const float* xb1 = x1 + (size_t)b * CIN1 * (H * W);
    const float* xb2 = (CIN2 > 0) ? (x2 + (size_t)b * CIN2 * (H * W)) : nullptr;

    auto xplane = [&](int ci) -> const float* {
        if constexpr (CIN2 > 0)
            return (ci < CIN1) ? (xb1 + ci * (H * W)) : (xb2 + (ci - CIN1) * (H * W));
        else
            return xb1 + ci * (H * W);
    };
    auto load_taps = [&](int ci, float v[6][3]) {
        const float* xp = xplane(ci);
        #pragma unroll
        for (int rr = 0; rr < 6; ++rr)
            #pragma unroll
            for (int dc = 0; dc < 3; ++dc)
                v[rr][dc] = xp[base + rr * W + dc];
    };
    auto fma_taps = [&](int ci, const float v[6][3]) {
        float mv[6][3];
        #pragma unroll
        for (int rr = 0; rr < 6; ++rr)
            #pragma unroll
            for (int dc = 0; dc < 3; ++dc)
                mv[rr][dc] = v[rr][dc] * m[rr][dc];
        const float4* wp = (const float4*)&wlds[ci * 72];
        #pragma unroll
        for (int k = 0; k < 9; ++k) {
            const float4 wA = wp[k * 2];
            const float4 wB = wp[k * 2 + 1];
            const int kh = k / 3, kw = k % 3;
            #pragma unroll
            for (int rr = 0; rr < 4; ++rr) {
                const float tap = mv[rr + kh][kw];
                acc[rr][0][0] = fmaf(tap, wA.x, acc[rr][0][0]);
                acc[rr][0][1] = fmaf(tap, wA.y, acc[rr][0][1]);
                acc[rr][0][2] = fmaf(tap, wA.z, acc[rr][0][2]);
                acc[rr][0][3] = fmaf(tap, wA.w, acc[rr][0][3]);
                acc[rr][1][0] = fmaf(tap, wB.x, acc[rr][1][0]);
                acc[rr][1][1] = fmaf(tap, wB.y, acc[rr][1][1]);
                acc[rr][1][2] = fmaf(tap, wB.z, acc[rr][1][2]);
                acc[rr][1][3] = fmaf(tap, wB.w, acc[rr][1][3]);
            }
        }
    };

    float vA[6][3], vB[6][3];
    load_taps(0, vA);
    #pragma unroll 1
    for (int ci = 0; ci + 2 <= CIN; ci += 2) {
        load_taps(ci + 1, vB);
        fma_taps(ci, vA);
        if (ci + 2 < CIN) load_taps(ci + 2, vA);
        fma_taps(ci + 1, vB);
    }
    if constexpr (CIN & 1) {
        fma_taps(CIN - 1, vA);
    }

    float s[4][CG];
    #pragma unroll
    for (int rr = 0; rr < 4; ++rr)
        #pragma unroll
        for (int j = 0; j < CG; ++j)
            s[rr][j] = gt[0] * fmaxf(acc[rr][j][0], 0.f)
                     + gt[1] * fmaxf(acc[rr][j][1], 0.f)
                     + gt[2] * fmaxf(acc[rr][j][2], 0.f)
                     + gt[3] * fmaxf(acc[rr][j][3], 0.f);

    #pragma unroll
    for (int j = 0; j < CG; ++j) {
        float* op = out + ((size_t)b * COUT + c0 + j) * (H * W) + h0 * W + w;
        #pragma unroll
        for (int rr = 0; rr < 4; ++rr)
            if (h0 + rr < H) op[rr * W] = s[rr][j];
    }

    if constexpr (POOL) {
        constexpr int H2 = H / 2, W2 = W / 2;
        #pragma unroll
        for (int j = 0; j < CG; ++j) {
            float cm0 = fmaxf(s[0][j], s[1][j]);
            float cm1 = fmaxf(s[2][j], s[3][j]);
            const float o0 = fmaxf(cm0, __shfl_xor(cm0, 1, 64));
            const float o1 = fmaxf(cm1, __shfl_xor(cm1, 1, 64));
            if ((w & 1) == 0) {
                const int pr0 = h0 >> 1;
                float* pp = pout + ((size_t)b * COUT + c0 + j) * (H2 * W2) + (w >> 1);
                if (pr0     < H2) pp[pr0 * W2]       = o0;
                if (pr0 + 1 < H2) pp[(pr0 + 1) * W2] = o1;
            }
        }
    }
}

// ---------------- bilinear x2 upsample, align_corners=True ----------------
template <int N>
__global__ __launch_bounds__(256) void upsample2(
    const float* __restrict__ in, float* __restrict__ out, int BC)
{
    constexpr int M = 2 * N;
    const int idx = blockIdx.x * 256 + threadIdx.x;
    const int total = BC * M * M;
    if (idx >= total) return;
    const int x = idx % M;
    int tmp = idx / M;
    const int y = tmp % M;
    const int bc = tmp / M;
    const float scale = (float)((double)(N - 1) / (double)(M - 1));
    const float cy = (float)y * scale;
    const float cx = (float)x * scale;
    const int iy0 = (int)floorf(cy);
    const int ix0 = (int)floorf(cx);
    const int iy1 = min(iy0 + 1, N - 1);
    const int ix1 = min(ix0 + 1, N - 1);
    const float wy = cy - (float)iy0;
    const float wx = cx - (float)ix0;
    const float* p = in + (size_t)bc * N * N;
    const float v00 = p[iy0 * N + ix0], v01 = p[iy0 * N + ix1];
    const float v10 = p[iy1 * N + ix0], v11 = p[iy1 * N + ix1];
    const float a0 = v00 * (1.0f - wy) + v10 * wy;
    const float a1 = v01 * (1.0f - wy) + v11 * wy;
    out[idx] = a0 * (1.0f - wx) + a1 * wx;
}

// ---------------------------------------------------------------------------
extern "C" void kernel_launch(void* const* d_in, const int* in_sizes, int n_in,
                              void* d_out, int out_size, void* d_ws, size_t ws_size,
                              hipStream_t stream)
{
    const float* x = (const float*)d_in[0];
    const float* cw[5]; const float* cb[5]; const float* gw[5]; const float* gb[5];
    const float* nw[5]; const float* nb[5]; const float* epsv[5];
    for (int l = 0; l < 5; ++l) {
        cw[l]   = (const float*)d_in[1 + 7 * l + 0];
        cb[l]   = (const float*)d_in[1 + 7 * l + 1];
        gw[l]   = (const float*)d_in[1 + 7 * l + 2];
        gb[l]   = (const float*)d_in[1 + 7 * l + 3];
        nw[l]   = (const float*)d_in[1 + 7 * l + 4];
        nb[l]   = (const float*)d_in[1 + 7 * l + 5];
        epsv[l] = (const float*)d_in[1 + 7 * l + 6];
    }
    const float* wlast = (const float*)d_in[36];
    const float* blast = (const float*)d_in[37];
    const int*   kp    = (const int*)d_in[38];
    float* out = (float*)d_out;
    float* ws  = (float*)d_ws;

    float* conv1 = ws + O_CONV1;
    float* xpad  = ws + O_XPAD;
    float* p1    = ws + O_P1;
    float* conv2 = ws + O_CONV2;
    float* p2    = ws + O_P2;
    float* conv3 = ws + O_CONV3;
    float* up3   = ws + O_UP3;
    float* m4    = ws + O_M4;
    float* up4   = ws + O_UP4;
    float* graw[5]; float* cs[5];
    for (int l = 0; l < 5; ++l) {
        graw[l] = ws + O_GRAW + (size_t)l * BATCH * 4;
        cs[l]   = ws + O_CS + (size_t)l * 64;
    }

    hipMemsetAsync(out, 0, (size_t)out_size * sizeof(float), stream);
    hipMemcpyAsync(xpad, x, (size_t)BATCH * 784 * sizeof(float),
                   hipMemcpyDeviceToDevice, stream);

    #define CDIV(a) (((a) + 255) / 256)
    const int gq  = 784 * 5;            // quad conv grids (L1, L5)
    const int g2  = pb4(14, 14) * 5;
    const int g3  = pb4(7, 7)   * 10;
    const int g4  = pb4(14, 14) * 5;
    const int GB2 = BATCH / 2;          // 2 samples per gate block

    // ---- layer 1: x [B,1,28,28] -> conv1 + p1 (fused pool)
    gate_block_v4<784, 0><<<GB2, 256, 0, stream>>>(
        x, nullptr, gw[0], gb[0], nw[0], nb[0], epsv[0], graw[0]);
    gate_reduce<<<1, 256, 0, stream>>>(graw[0], cs[0]);
    moe_conv_q4<1, 0, 10, 1, 0><<<gq, 256, 0, stream>>>(
        xpad, nullptr, cw[0], cb[0], graw[0], cs[0], kp, conv1, p1,
        nullptr, nullptr);

    // ---- layer 2: p1 -> conv2 + p2 (fused pool)
    gate_block_v4<1960, 0><<<GB2, 256, 0, stream>>>(
        p1, nullptr, gw[1], gb[1], nw[1], nb[1], epsv[1], graw[1]);
    gate_reduce<<<1, 256, 0, stream>>>(graw[1], cs[1]);
    moe_conv4<10, 0, 10, 14, 14, 1><<<g2, 256, 0, stream>>>(
        p1, nullptr, cw[1], cb[1], graw[1], cs[1], kp, conv2, p2);

    // ---- layer 3: p2 -> conv3 -> up3
    gate_block_s<490><<<BATCH, 256, 0, stream>>>(
        p2, gw[2], gb[2], nw[2], nb[2], epsv[2], graw[2]);
    gate_reduce<<<1, 256, 0, stream>>>(graw[2], cs[2]);
    moe_conv4<10, 0, 20, 7, 7, 0><<<g3, 256, 0, stream>>>(
        p2, nullptr, cw[2], cb[2], graw[2], cs[2], kp, conv3, nullptr);
    upsample2<7><<<CDIV(BATCH * 20 * 196), 256, 0, stream>>>(conv3, up3, BATCH * 20);

    // ---- layer 4: [up3 | conv2] -> m4 -> up4
    gate_block_v4<3920, 1960><<<GB2, 256, 0, stream>>>(
        up3, conv2, gw[3], gb[3], nw[3], nb[3], epsv[3], graw[3]);
    gate_reduce<<<1, 256, 0, stream>>>(graw[3], cs[3]);
    moe_conv4<20, 10, 10, 14, 14, 0><<<g4, 256, 0, stream>>>(
        up3, conv2, cw[3], cb[3], graw[3], cs[3], kp, m4, nullptr);
    upsample2<14><<<CDIV(BATCH * 10 * 784), 256, 0, stream>>>(m4, up4, BATCH * 10);

    // ---- layer 5: [up4 | conv1] -> fused (conv + gate + final 1x1) -> out
    gate_block_v4<7840, 7840><<<GB2, 256, 0, stream>>>(
        up4, conv1, gw[4], gb[4], nw[4], nb[4], epsv[4], graw[4]);
    gate_reduce<<<1, 256, 0, stream>>>(graw[4], cs[4]);
    moe_conv_q4<10, 10, 10, 0, 1><<<gq, 256, 0, stream>>>(
        up4, conv1, cw[4], cb[4], graw[4], cs[4], kp, out, nullptr,
        wlast, blast);
    #undef CDIV
}